// Round 1
// baseline (303.730 us; speedup 1.0000x reference)
//
#include <hip/hip_runtime.h>

#define NN 8192
#define DD 128

typedef __bf16 bf16x8 __attribute__((ext_vector_type(8)));
typedef float f32x4 __attribute__((ext_vector_type(4)));

__device__ inline unsigned short f2bf(float f) {
  unsigned u = __float_as_uint(f);
  u += 0x7FFFu + ((u >> 16) & 1u);   // round-to-nearest-even
  return (unsigned short)(u >> 16);
}

// Kernel 1: convert inputs f32->bf16, compute row sq-norms (fp32), zero output.
__global__ __launch_bounds__(256) void prep_kernel(const float* __restrict__ x,
                                                   unsigned short* __restrict__ xb,
                                                   float* __restrict__ sq,
                                                   float* __restrict__ out) {
  const int wave = threadIdx.x >> 6, lane = threadIdx.x & 63;
  const int row = blockIdx.x * 4 + wave;
  const float2 v = ((const float2*)(x + (size_t)row * DD))[lane];
  float ss = v.x * v.x + v.y * v.y;
  #pragma unroll
  for (int off = 32; off; off >>= 1) ss += __shfl_down(ss, off);
  if (lane == 0) sq[row] = ss;
  unsigned packed = (unsigned)f2bf(v.x) | ((unsigned)f2bf(v.y) << 16);
  ((unsigned*)(xb + (size_t)row * DD))[lane] = packed;
  if (blockIdx.x == 0 && threadIdx.x == 0) out[0] = 0.0f;
}

// Kernel 2: fused bf16-MFMA score tiles + streaming per-row top-5.
// Block = 64 rows x 2048 cols (grid 128 x 4). Score s_ij = sq[j] - 2*dot(i,j).
__global__ __launch_bounds__(256) void dist_topk_kernel(
    const unsigned short* __restrict__ xb, const float* __restrict__ sq,
    float* __restrict__ pscore, int* __restrict__ pidx) {
  const int t = threadIdx.x;
  const int wave = t >> 6, lane = t & 63;
  const int lrow = lane & 15, lquad = lane >> 4;
  const int rowBase = blockIdx.x * 64;
  const int chunk = blockIdx.y;                    // cols [chunk*2048, +2048)

  __shared__ unsigned short colsB[64 * DD];        // 16 KB, XOR-swizzled 16B chunks
  __shared__ float scores[64 * 65];                // +1 pad: 2-way reads (free)
  __shared__ float sqs[64];
  __shared__ float mS[64 * 4 * 5];
  __shared__ int   mI[64 * 4 * 5];

  // A fragments: wave's 16 rows, K=128 in 4 MFMA k-steps.
  // lane holds A[m=lane&15][k=(lane>>4)*8 + j], j=0..7  (verified m89/m91 layout)
  const int arow = rowBase + wave * 16 + lrow;
  bf16x8 afrag[4];
  const unsigned short* aptr = xb + (size_t)arow * DD + lquad * 8;
  #pragma unroll
  for (int s = 0; s < 4; ++s) afrag[s] = *(const bf16x8*)(aptr + s * 32);

  float ts[5]; int ti[5];
  #pragma unroll
  for (int k = 0; k < 5; ++k) { ts[k] = 3.0e38f; ti[k] = 0x7FFFFFFF; }

  const int selRow = t & 63;   // selection: thread scans this row,
  const int selQ   = t >> 6;   // over col-quarter [selQ*16, +16) of each 64-chunk

  const int j0 = chunk * 2048;
  for (int jt = j0; jt < j0 + 2048; jt += 64) {
    // Stage 64 candidate rows (contiguous 16 KB in global) into LDS.
    {
      const float4* srcv = (const float4*)(xb + (size_t)jt * DD);
      float4* dstv = (float4*)colsB;
      #pragma unroll
      for (int g = t; g < 1024; g += 256) {
        int r = g >> 4, ch = g & 15;
        dstv[(r << 4) | (ch ^ (r & 15))] = srcv[g];   // XOR swizzle, bank-uniform
      }
      if (t < 64) sqs[t] = sq[jt + t];
    }
    __syncthreads();

    // Each wave: its 16 rows x 64 cols (4 col sub-tiles of 16).
    #pragma unroll
    for (int ct = 0; ct < 4; ++ct) {
      const unsigned short* bb = colsB + (ct * 16 + lrow) * DD;
      bf16x8 bfr[4];
      #pragma unroll
      for (int s = 0; s < 4; ++s)
        bfr[s] = *(const bf16x8*)(bb + ((((s << 2) + lquad) ^ lrow) << 3));
      f32x4 acc = {0.f, 0.f, 0.f, 0.f};
      #pragma unroll
      for (int s = 0; s < 4; ++s)
        acc = __builtin_amdgcn_mfma_f32_16x16x32_bf16(afrag[s], bfr[s], acc, 0, 0, 0);
      // D: col = lane&15, row = (lane>>4)*4 + reg
      const int lc = ct * 16 + lrow;
      const float sqc = sqs[lc];
      #pragma unroll
      for (int r = 0; r < 4; ++r) {
        int lr = wave * 16 + lquad * 4 + r;
        scores[lr * 65 + lc] = sqc - 2.0f * acc[r];
      }
    }
    __syncthreads();

    // Streaming top-5 (ascending j within thread => strict '<' keeps earliest idx)
    const float* srow = &scores[selRow * 65 + selQ * 16];
    const int jb = jt + selQ * 16;
    #pragma unroll
    for (int c = 0; c < 16; ++c) {
      float sv = srow[c];
      if (sv < ts[4]) {
        ts[4] = sv; ti[4] = jb + c;
        #pragma unroll
        for (int p = 4; p > 0; --p) {
          bool sw = (ts[p] < ts[p-1]) || (ts[p] == ts[p-1] && ti[p] < ti[p-1]);
          if (sw) { float a = ts[p]; ts[p] = ts[p-1]; ts[p-1] = a;
                    int   b = ti[p]; ti[p] = ti[p-1]; ti[p-1] = b; }
        }
      }
    }
  }

  // Merge the 4 per-quarter lists of each row -> block-level top-5.
  __syncthreads();
  #pragma unroll
  for (int k = 0; k < 5; ++k) {
    mS[(selRow * 4 + selQ) * 5 + k] = ts[k];
    mI[(selRow * 4 + selQ) * 5 + k] = ti[k];
  }
  __syncthreads();
  if (t < 64) {
    float fs[5]; int fi[5];
    #pragma unroll
    for (int k = 0; k < 5; ++k) { fs[k] = 3.0e38f; fi[k] = 0x7FFFFFFF; }
    for (int q = 0; q < 4; ++q) {
      #pragma unroll
      for (int k = 0; k < 5; ++k) {
        float sv = mS[(t * 4 + q) * 5 + k];
        int jv = mI[(t * 4 + q) * 5 + k];
        if (sv < fs[4] || (sv == fs[4] && jv < fi[4])) {
          fs[4] = sv; fi[4] = jv;
          #pragma unroll
          for (int p = 4; p > 0; --p) {
            bool sw = (fs[p] < fs[p-1]) || (fs[p] == fs[p-1] && fi[p] < fi[p-1]);
            if (sw) { float a = fs[p]; fs[p] = fs[p-1]; fs[p-1] = a;
                      int   b = fi[p]; fi[p] = fi[p-1]; fi[p-1] = b; }
          }
        }
      }
    }
    const int row = rowBase + t;
    const size_t base = ((size_t)chunk * NN + row) * 5;
    #pragma unroll
    for (int k = 0; k < 5; ++k) { pscore[base + k] = fs[k]; pidx[base + k] = fi[k]; }
  }
}

// Kernel 3: merge 4 col-chunk partial top-5 lists -> neg index (5th smallest).
__global__ __launch_bounds__(256) void merge_kernel(const float* __restrict__ pscore,
                                                    const int* __restrict__ pidx,
                                                    int* __restrict__ negidx) {
  const int r = blockIdx.x * 256 + threadIdx.x;
  float fs[5]; int fi[5];
  #pragma unroll
  for (int k = 0; k < 5; ++k) { fs[k] = 3.0e38f; fi[k] = 0x7FFFFFFF; }
  for (int cb = 0; cb < 4; ++cb) {
    const size_t base = ((size_t)cb * NN + r) * 5;
    #pragma unroll
    for (int k = 0; k < 5; ++k) {
      float sv = pscore[base + k];
      int jv = pidx[base + k];
      if (sv < fs[4] || (sv == fs[4] && jv < fi[4])) {
        fs[4] = sv; fi[4] = jv;
        #pragma unroll
        for (int p = 4; p > 0; --p) {
          bool sw = (fs[p] < fs[p-1]) || (fs[p] == fs[p-1] && fi[p] < fi[p-1]);
          if (sw) { float a = fs[p]; fs[p] = fs[p-1]; fs[p-1] = a;
                    int   b = fi[p]; fi[p] = fi[p-1]; fi[p-1] = b; }
        }
      }
    }
  }
  negidx[r] = fi[4];
}

// Kernel 4: exact fp32 hinge per row (wave per row) + mean via atomics.
__global__ __launch_bounds__(256) void final_kernel(const float* __restrict__ x,
                                                    const float* __restrict__ pos,
                                                    const int* __restrict__ negidx,
                                                    float* __restrict__ out) {
  const int wave = threadIdx.x >> 6, lane = threadIdx.x & 63;
  const int row = blockIdx.x * 4 + wave;
  const int nidx = negidx[row];
  const float2 xv = ((const float2*)(x   + (size_t)row  * DD))[lane];
  const float2 pv = ((const float2*)(pos + (size_t)row  * DD))[lane];
  const float2 nv = ((const float2*)(x   + (size_t)nidx * DD))[lane];
  float a0 = xv.x - pv.x + 1e-6f, a1 = xv.y - pv.y + 1e-6f;
  float b0 = xv.x - nv.x + 1e-6f, b1 = xv.y - nv.y + 1e-6f;
  float dap = a0 * a0 + a1 * a1;
  float dan = b0 * b0 + b1 * b1;
  #pragma unroll
  for (int off = 32; off; off >>= 1) {
    dap += __shfl_down(dap, off);
    dan += __shfl_down(dan, off);
  }
  __shared__ float hs[4];
  if (lane == 0) hs[wave] = fmaxf(sqrtf(dap) - sqrtf(dan) + 0.3f, 0.0f);
  __syncthreads();
  if (threadIdx.x == 0) {
    float s = hs[0] + hs[1] + hs[2] + hs[3];
    atomicAdd(out, s * (1.0f / 8192.0f));
  }
}

extern "C" void kernel_launch(void* const* d_in, const int* in_sizes, int n_in,
                              void* d_out, int out_size, void* d_ws, size_t ws_size,
                              hipStream_t stream) {
  const float* x   = (const float*)d_in[0];
  const float* pos = (const float*)d_in[1];
  float* out = (float*)d_out;

  char* w = (char*)d_ws;
  unsigned short* xb = (unsigned short*)w;                     // NN*DD*2 = 2 MB
  float* sq = (float*)(w + (size_t)NN * DD * 2);               // 32 KB
  char* w2 = w + (size_t)NN * DD * 2 + (size_t)NN * 4;
  float* pscore = (float*)w2;                                  // 4*NN*5*4 = 640 KB
  int*   pidx   = (int*)(w2 + (size_t)4 * NN * 5 * 4);         // 640 KB
  int*   negidx = (int*)(w2 + (size_t)8 * NN * 5 * 4);         // 32 KB

  prep_kernel<<<NN / 4, 256, 0, stream>>>(x, xb, sq, out);
  dist_topk_kernel<<<dim3(NN / 64, 4), 256, 0, stream>>>(xb, sq, pscore, pidx);
  merge_kernel<<<NN / 256, 256, 0, stream>>>(pscore, pidx, negidx);
  final_kernel<<<NN / 4, 256, 0, stream>>>(x, pos, negidx, out);
}

// Round 2
// 248.617 us; speedup vs baseline: 1.2217x; 1.2217x over previous
//
#include <hip/hip_runtime.h>

#define NN 8192
#define DD 128
#define CH 8            // column chunks
#define CPC (NN / CH)   // cols per chunk = 1024
#define TILES (CPC / 64)

typedef __bf16 bf16x8 __attribute__((ext_vector_type(8)));
typedef float f32x4 __attribute__((ext_vector_type(4)));

__device__ inline unsigned short f2bf(float f) {
  unsigned u = __float_as_uint(f);
  u += 0x7FFFu + ((u >> 16) & 1u);   // round-to-nearest-even
  return (unsigned short)(u >> 16);
}

// Lexicographic (score, idx) sorted-5 insert; prefers smaller idx on ties.
__device__ inline void insert5(float (&s)[5], int (&i5)[5], float sv, int jv) {
  if (sv < s[4] || (sv == s[4] && jv < i5[4])) {
    s[4] = sv; i5[4] = jv;
#pragma unroll
    for (int p = 4; p > 0; --p) {
      bool sw = (s[p] < s[p - 1]) || (s[p] == s[p - 1] && i5[p] < i5[p - 1]);
      if (sw) {
        float a = s[p]; s[p] = s[p - 1]; s[p - 1] = a;
        int   b = i5[p]; i5[p] = i5[p - 1]; i5[p - 1] = b;
      }
    }
  }
}

// Kernel 1: f32->bf16 convert, fp32 row sq-norms, zero output scalar.
__global__ __launch_bounds__(256) void prep_kernel(const float* __restrict__ x,
                                                   unsigned short* __restrict__ xb,
                                                   float* __restrict__ sq,
                                                   float* __restrict__ out) {
  const int wave = threadIdx.x >> 6, lane = threadIdx.x & 63;
  const int row = blockIdx.x * 4 + wave;
  const float2 v = ((const float2*)(x + (size_t)row * DD))[lane];
  float ss = v.x * v.x + v.y * v.y;
#pragma unroll
  for (int off = 32; off; off >>= 1) ss += __shfl_down(ss, off);
  if (lane == 0) sq[row] = ss;
  unsigned packed = (unsigned)f2bf(v.x) | ((unsigned)f2bf(v.y) << 16);
  ((unsigned*)(xb + (size_t)row * DD))[lane] = packed;
  if (blockIdx.x == 0 && threadIdx.x == 0) out[0] = 0.0f;
}

// Kernel 2: bf16-MFMA score tiles with in-register streaming top-5.
// Block = 64 rows x 1024 cols; grid (128, 8) = 1024 blocks (4/CU).
// Score s_ij = sq[j] - 2*dot(i,j)  (monotone in dist_ij per row i).
__global__ __launch_bounds__(256) void dist_topk_kernel(
    const unsigned short* __restrict__ xb, const float* __restrict__ sq,
    float* __restrict__ pscore, unsigned short* __restrict__ pidx) {
  const int t = threadIdx.x;
  const int wave = t >> 6, lane = t & 63;
  const int lrow = lane & 15, lquad = lane >> 4;
  const int rowBase = blockIdx.x * 64;
  const int chunk = blockIdx.y;
  const int j0 = chunk * CPC;

  __shared__ unsigned short colsB[2][64 * DD];   // 2 x 16 KB, XOR-swizzled 16B chunks
  __shared__ float sqs[2][64];

  // A fragments: lane holds A[m=lane&15][k=(lane>>4)*8 + j], j=0..7
  const int arow = rowBase + wave * 16 + lrow;
  bf16x8 afrag[4];
  {
    const unsigned short* aptr = xb + (size_t)arow * DD + lquad * 8;
#pragma unroll
    for (int s = 0; s < 4; ++s) afrag[s] = *(const bf16x8*)(aptr + s * 32);
  }

  // Per-lane top-5 lists for 4 rows (rows wave*16 + lquad*4 + r).
  float ts[4][5]; int ti[4][5];
#pragma unroll
  for (int r = 0; r < 4; ++r)
#pragma unroll
    for (int k = 0; k < 5; ++k) { ts[r][k] = 3.0e38f; ti[r][k] = 0x7FFFFFFF; }

  // Prefetch tile 0 into registers.
  float4 stg[4];
  float sqv = 0.0f;
  {
    const float4* srcv = (const float4*)(xb + (size_t)j0 * DD);
#pragma unroll
    for (int i = 0; i < 4; ++i) stg[i] = srcv[t + i * 256];
    if (t < 64) sqv = sq[j0 + t];
  }

  for (int it = 0; it < TILES; ++it) {
    const int jt = j0 + it * 64;
    const int cur = it & 1;
    // Commit staged tile to LDS (XOR swizzle: chunk ch of row r -> ch^(r&15)).
    {
      float4* dstv = (float4*)colsB[cur];
#pragma unroll
      for (int i = 0; i < 4; ++i) {
        int g = t + i * 256;
        int r = g >> 4, ch = g & 15;
        dstv[(r << 4) | (ch ^ (r & 15))] = stg[i];
      }
      if (t < 64) sqs[cur][t] = sqv;
    }
    __syncthreads();

    // Prefetch next tile (overlaps with compute below).
    if (it + 1 < TILES) {
      const float4* srcv = (const float4*)(xb + (size_t)(jt + 64) * DD);
#pragma unroll
      for (int i = 0; i < 4; ++i) stg[i] = srcv[t + i * 256];
      if (t < 64) sqv = sq[jt + 64 + t];
    }

    // Compute 64x64 scores; select in-register from accumulator.
#pragma unroll
    for (int ct = 0; ct < 4; ++ct) {
      const unsigned short* bb = &colsB[cur][(ct * 16 + lrow) * DD];
      bf16x8 bfr[4];
#pragma unroll
      for (int s = 0; s < 4; ++s)
        bfr[s] = *(const bf16x8*)(bb + ((((s << 2) + lquad) ^ lrow) << 3));
      f32x4 acc = {0.f, 0.f, 0.f, 0.f};
#pragma unroll
      for (int s = 0; s < 4; ++s)
        acc = __builtin_amdgcn_mfma_f32_16x16x32_bf16(afrag[s], bfr[s], acc, 0, 0, 0);
      // D layout: col = lane&15, row = (lane>>4)*4 + reg
      const int col = jt + ct * 16 + lrow;
      const float sqc = sqs[cur][ct * 16 + lrow];
#pragma unroll
      for (int r = 0; r < 4; ++r)
        insert5(ts[r], ti[r], sqc - 2.0f * acc[r], col);
    }
    __syncthreads();   // safe to overwrite colsB[cur^1] next iteration
  }

  // Merge across the 16 lanes (same lquad share rows) via xor-shuffles.
#pragma unroll
  for (int r = 0; r < 4; ++r) {
#pragma unroll
    for (int m = 1; m < 16; m <<= 1) {
      float os[5]; int oi[5];
#pragma unroll
      for (int k = 0; k < 5; ++k) {
        os[k] = __shfl_xor(ts[r][k], m);
        oi[k] = __shfl_xor(ti[r][k], m);
      }
#pragma unroll
      for (int k = 0; k < 5; ++k) insert5(ts[r], ti[r], os[k], oi[k]);
    }
  }
  if (lrow == 0) {
    const int row0 = rowBase + wave * 16 + lquad * 4;
#pragma unroll
    for (int r = 0; r < 4; ++r) {
      const size_t base = ((size_t)chunk * NN + row0 + r) * 5;
#pragma unroll
      for (int k = 0; k < 5; ++k) {
        pscore[base + k] = ts[r][k];
        pidx[base + k] = (unsigned short)ti[r][k];
      }
    }
  }
}

// Kernel 3: fused chunk-merge (5th-smallest -> neg idx) + exact fp32 hinge + mean.
__global__ __launch_bounds__(256) void final_kernel(const float* __restrict__ x,
                                                    const float* __restrict__ pos,
                                                    const float* __restrict__ pscore,
                                                    const unsigned short* __restrict__ pidx,
                                                    float* __restrict__ out) {
  const int wave = threadIdx.x >> 6, lane = threadIdx.x & 63;
  const int row = blockIdx.x * 4 + wave;

  int nv = 0;
  if (lane == 0) {
    float fs[5]; int fi[5];
#pragma unroll
    for (int k = 0; k < 5; ++k) { fs[k] = 3.0e38f; fi[k] = 0x7FFFFFFF; }
    for (int cb = 0; cb < CH; ++cb) {
      const size_t base = ((size_t)cb * NN + row) * 5;
#pragma unroll
      for (int k = 0; k < 5; ++k)
        insert5(fs, fi, pscore[base + k], (int)pidx[base + k]);
    }
    nv = fi[4];
  }
  const int nidx = __shfl(nv, 0);

  const float2 xv = ((const float2*)(x   + (size_t)row  * DD))[lane];
  const float2 pv = ((const float2*)(pos + (size_t)row  * DD))[lane];
  const float2 nvv = ((const float2*)(x  + (size_t)nidx * DD))[lane];
  float a0 = xv.x - pv.x + 1e-6f, a1 = xv.y - pv.y + 1e-6f;
  float b0 = xv.x - nvv.x + 1e-6f, b1 = xv.y - nvv.y + 1e-6f;
  float dap = a0 * a0 + a1 * a1;
  float dan = b0 * b0 + b1 * b1;
#pragma unroll
  for (int off = 32; off; off >>= 1) {
    dap += __shfl_down(dap, off);
    dan += __shfl_down(dan, off);
  }
  __shared__ float hs[4];
  if (lane == 0) hs[wave] = fmaxf(sqrtf(dap) - sqrtf(dan) + 0.3f, 0.0f);
  __syncthreads();
  if (threadIdx.x == 0) {
    float s = hs[0] + hs[1] + hs[2] + hs[3];
    atomicAdd(out, s * (1.0f / 8192.0f));
  }
}

extern "C" void kernel_launch(void* const* d_in, const int* in_sizes, int n_in,
                              void* d_out, int out_size, void* d_ws, size_t ws_size,
                              hipStream_t stream) {
  const float* x   = (const float*)d_in[0];
  const float* pos = (const float*)d_in[1];
  float* out = (float*)d_out;

  char* w = (char*)d_ws;
  unsigned short* xb = (unsigned short*)w;                       // 2 MB
  float* sq = (float*)(w + (size_t)NN * DD * 2);                 // 32 KB
  char* w2 = w + (size_t)NN * DD * 2 + (size_t)NN * 4;
  float* pscore = (float*)w2;                                    // CH*NN*5*4 = 1.31 MB
  unsigned short* pidx = (unsigned short*)(w2 + (size_t)CH * NN * 5 * 4);  // 0.66 MB

  prep_kernel<<<NN / 4, 256, 0, stream>>>(x, xb, sq, out);
  dist_topk_kernel<<<dim3(NN / 64, CH), 256, 0, stream>>>(xb, sq, pscore, pidx);
  final_kernel<<<NN / 4, 256, 0, stream>>>(x, pos, pscore, pidx, out);
}